// Round 4
// baseline (176.066 us; speedup 1.0000x reference)
//
#include <hip/hip_runtime.h>
#include <hip/hip_fp16.h>
#include <math.h>

// GraphAttention: Q=4, N=50000, K=8, F_IN=128, F_OUT=64
//   y  = query @ W1        (MFMA: A=bf16(query), B=W1 split hi+lo bf16; f16 out)
//   s1 = tanh(mean_k y[e]+b1) . W2
//   score = mean_k s1[e] + b2
//   softmax without max-sub (scores bounded ~|2|): w=exp(s)/Z
//   ctx = (sum_n exp(s_n) * values[n]) / Z

#define FIN 128
#define FOUT 64
#define KN 8

typedef short bf16x8 __attribute__((ext_vector_type(8)));
typedef float f32x4 __attribute__((ext_vector_type(4)));

__device__ inline short f2bf(float x) {
    unsigned u = __float_as_uint(x);
    unsigned r = (u + 0x7fffu + ((u >> 16) & 1u)) >> 16;
    return (short)r;
}
__device__ inline float bf2f(short s) {
    return __uint_as_float(((unsigned)(unsigned short)s) << 16);
}
__device__ inline unsigned pkadd(unsigned a, unsigned b) {
    __half2 ha = *(__half2*)&a, hb = *(__half2*)&b;
    __half2 r = __hadd2(ha, hb);
    return *(unsigned*)&r;
}

// ---------------- Stage 0: pack W1 (hi/lo bf16 MFMA B-frags); zero Z, ctx ----------------
__global__ __launch_bounds__(512) void k_prep(const float* __restrict__ W1,
                                              short* __restrict__ W1pk,
                                              float* __restrict__ Z,
                                              float* __restrict__ ctx, int Q) {
    const int tid = threadIdx.x;
    for (int it = 0; it < 2; ++it) {
        int p = tid + it * 512;
        int f = p >> 6, lane = p & 63;
        int kk = f >> 2, nt = f & 3;
        int lg = lane >> 4, lr = lane & 15;
        #pragma unroll
        for (int j = 0; j < 8; ++j) {
            float w = W1[(kk * 32 + lg * 8 + j) * FOUT + nt * 16 + lr];
            short h = f2bf(w);
            W1pk[(size_t)p * 8 + j] = h;                           // hi bank
            W1pk[1024 * 8 + (size_t)p * 8 + j] = f2bf(w - bf2f(h)); // lo bank
        }
    }
    if (tid < Q * FIN) ctx[tid] = 0.f;
    if (tid < Q) Z[tid] = 0.f;
}

// ---------------- Stage 1: y = query @ W1 ----------------
// t-outer: 8 upfront float4 loads per 16-node tile (deep MLP), 2 MFMA per (kk,nt).
__global__ __launch_bounds__(256, 4) void k_xw(const float* __restrict__ query,
                                               const short* __restrict__ W1pk,
                                               __half* __restrict__ y, int N) {
    const int tid = threadIdx.x;
    const int wave = tid >> 6, lane = tid & 63;
    const int lg = lane >> 4, lr = lane & 15;
    const int q = blockIdx.y;
    const int blockBase = blockIdx.x * 256;
    const float* qb = query + (size_t)q * N * FIN;
    __half* yq = y + (size_t)q * N * FOUT;
    const bf16x8* Bp = (const bf16x8*)W1pk;   // [2][16][64] frags

    #pragma unroll
    for (int t = 0; t < 4; ++t) {
        int node = blockBase + wave * 64 + t * 16 + lr;
        int nc = node < N ? node : N - 1;
        const float4* ap = (const float4*)(qb + (size_t)nc * FIN);
        float4 a0 = ap[0 * 8 + lg * 2], a1 = ap[0 * 8 + lg * 2 + 1];
        float4 a2 = ap[1 * 8 + lg * 2], a3 = ap[1 * 8 + lg * 2 + 1];
        float4 a4 = ap[2 * 8 + lg * 2], a5 = ap[2 * 8 + lg * 2 + 1];
        float4 a6 = ap[3 * 8 + lg * 2], a7 = ap[3 * 8 + lg * 2 + 1];
        float4 av[8] = {a0, a1, a2, a3, a4, a5, a6, a7};
        bf16x8 A[4];
        #pragma unroll
        for (int kk = 0; kk < 4; ++kk) {
            const float* xs = (const float*)&av[2 * kk];
            #pragma unroll
            for (int j = 0; j < 8; ++j) A[kk][j] = f2bf(xs[j]);
        }
        f32x4 acc[4];
        #pragma unroll
        for (int nt = 0; nt < 4; ++nt) acc[nt] = (f32x4)0.f;
        #pragma unroll
        for (int kk = 0; kk < 4; ++kk) {
            #pragma unroll
            for (int nt = 0; nt < 4; ++nt) {
                bf16x8 Bhi = Bp[(kk * 4 + nt) * 64 + lane];
                bf16x8 Blo = Bp[1024 + (kk * 4 + nt) * 64 + lane];
                acc[nt] = __builtin_amdgcn_mfma_f32_16x16x32_bf16(A[kk], Bhi, acc[nt], 0, 0, 0);
                acc[nt] = __builtin_amdgcn_mfma_f32_16x16x32_bf16(A[kk], Blo, acc[nt], 0, 0, 0);
            }
        }
        #pragma unroll
        for (int r = 0; r < 4; ++r) {
            int nodeO = blockBase + wave * 64 + t * 16 + lg * 4 + r;
            if (nodeO < N) {
                #pragma unroll
                for (int nt = 0; nt < 4; ++nt)
                    yq[(size_t)nodeO * FOUT + nt * 16 + lr] = __float2half(acc[nt][r]);
            }
        }
    }
}

// ---------------- Stage 2: s1 = tanh(mean_k y[e]+b1).W2 — one node per wave ----------------
// lane = k*8+c: single 16B gather covers all 8 neighbor rows per wave.
__global__ __launch_bounds__(256) void k_agg(const __half* __restrict__ y,
                                             const int* __restrict__ edges,
                                             const float* __restrict__ b1,
                                             const float* __restrict__ W2,
                                             float* __restrict__ s1, int N) {
    const int tid = threadIdx.x;
    const int wave = tid >> 6, lane = tid & 63;
    const int k = lane >> 3, c = lane & 7;
    const int n = blockIdx.x * 4 + wave;
    const int q = blockIdx.y;
    if (n >= N) return;
    const __half* yq = y + (size_t)q * N * FOUT;
    int e = edges[(size_t)n * KN + k];
    uint4 gv = *(const uint4*)(yq + (size_t)e * FOUT + c * 8);
    // k-reduce step 1 (xor 8) in packed f16
    unsigned u0 = pkadd(gv.x, (unsigned)__shfl_xor((int)gv.x, 8));
    unsigned u1 = pkadd(gv.y, (unsigned)__shfl_xor((int)gv.y, 8));
    unsigned u2 = pkadd(gv.z, (unsigned)__shfl_xor((int)gv.z, 8));
    unsigned u3 = pkadd(gv.w, (unsigned)__shfl_xor((int)gv.w, 8));
    // to f32
    __half2 h0 = *(__half2*)&u0, h1 = *(__half2*)&u1, h2 = *(__half2*)&u2, h3 = *(__half2*)&u3;
    float f0 = __low2float(h0), f1 = __high2float(h0);
    float f2 = __low2float(h1), f3 = __high2float(h1);
    float f4 = __low2float(h2), f5 = __high2float(h2);
    float f6 = __low2float(h3), f7 = __high2float(h3);
    // k-reduce steps 2,3 (xor 16, 32) in f32
    f0 += __shfl_xor(f0, 16); f1 += __shfl_xor(f1, 16);
    f2 += __shfl_xor(f2, 16); f3 += __shfl_xor(f3, 16);
    f4 += __shfl_xor(f4, 16); f5 += __shfl_xor(f5, 16);
    f6 += __shfl_xor(f6, 16); f7 += __shfl_xor(f7, 16);
    f0 += __shfl_xor(f0, 32); f1 += __shfl_xor(f1, 32);
    f2 += __shfl_xor(f2, 32); f3 += __shfl_xor(f3, 32);
    f4 += __shfl_xor(f4, 32); f5 += __shfl_xor(f5, 32);
    f6 += __shfl_xor(f6, 32); f7 += __shfl_xor(f7, 32);
    // transpose-extract: lane (k,c) takes element k -> owns feature f = c*8+k
    float e0 = (k & 1) ? f1 : f0;
    float e1 = (k & 1) ? f3 : f2;
    float e2 = (k & 1) ? f5 : f4;
    float e3 = (k & 1) ? f7 : f6;
    float e01 = (k & 2) ? e1 : e0;
    float e23 = (k & 2) ? e3 : e2;
    float sum = (k & 4) ? e23 : e01;
    const int f = c * 8 + k;
    float x = sum * 0.125f + b1[f];
    // fast tanh via exp
    float ax = fabsf(x);
    float ee = __expf(-2.f * ax);
    float th = __fdividef(1.f - ee, 1.f + ee);
    th = copysignf(th, x);
    float p = th * W2[f];
    #pragma unroll
    for (int off = 32; off; off >>= 1) p += __shfl_xor(p, off);
    if (lane == 0) s1[(size_t)q * N + n] = p;
}

// ---------------- Stage 3: score = mean_k s1[e]+b2; w_un = exp(score); Z += Σ ----------------
__global__ __launch_bounds__(256) void k_score(const float* __restrict__ s1,
                                               const int* __restrict__ edges,
                                               const float* __restrict__ b2,
                                               float* __restrict__ score,
                                               float* __restrict__ wun,
                                               float* __restrict__ Z, int N) {
    const int n = blockIdx.x * 256 + threadIdx.x;
    const int q = blockIdx.y;
    const float* s1q = s1 + (size_t)q * N;
    float ex = 0.f;
    if (n < N) {
        float acc = 0.f;
        #pragma unroll
        for (int k = 0; k < KN; ++k) acc += s1q[edges[n * KN + k]];
        float sc = acc * 0.125f + b2[0];
        score[(size_t)q * N + n] = sc;
        ex = expf(sc);
        wun[(size_t)q * N + n] = ex;
    }
    float p = ex;
    #pragma unroll
    for (int off = 32; off; off >>= 1) p += __shfl_xor(p, off);
    __shared__ float red[4];
    if ((threadIdx.x & 63) == 0) red[threadIdx.x >> 6] = p;
    __syncthreads();
    if (threadIdx.x == 0) atomicAdd(&Z[q], red[0] + red[1] + red[2] + red[3]);
}

// ---------------- Stage 4: ctx = (Σ w_un * values)/Z — unroll-8, deep MLP ----------------
__global__ __launch_bounds__(256, 4) void k_context(const float* __restrict__ values,
                                                    const float* __restrict__ wun,
                                                    const float* __restrict__ Z,
                                                    float* __restrict__ ctx, int N) {
    const int q = blockIdx.y, cb = blockIdx.x;   // 256 blocks per q
    const int tid = threadIdx.x;
    const int fi = tid & 31, g = tid >> 5;       // 8 node-groups x 32 float4-cols
    const float4* v = (const float4*)(values + (size_t)q * N * FIN);
    const float* w = wun + (size_t)q * N;
    const int chunk = (N + 255) >> 8;
    const int n0 = cb * chunk, n1 = min(n0 + chunk, N);
    float4 acc = make_float4(0.f, 0.f, 0.f, 0.f);
    int n = n0 + g;
    for (; n + 56 < n1; n += 64) {
        float w0 = w[n],      w1 = w[n + 8],  w2 = w[n + 16], w3 = w[n + 24];
        float w4 = w[n + 32], w5 = w[n + 40], w6 = w[n + 48], w7 = w[n + 56];
        float4 v0 = v[(size_t)n * 32 + fi];
        float4 v1 = v[(size_t)(n + 8) * 32 + fi];
        float4 v2 = v[(size_t)(n + 16) * 32 + fi];
        float4 v3 = v[(size_t)(n + 24) * 32 + fi];
        float4 v4 = v[(size_t)(n + 32) * 32 + fi];
        float4 v5 = v[(size_t)(n + 40) * 32 + fi];
        float4 v6 = v[(size_t)(n + 48) * 32 + fi];
        float4 v7 = v[(size_t)(n + 56) * 32 + fi];
        acc.x = fmaf(w0, v0.x, acc.x); acc.y = fmaf(w0, v0.y, acc.y);
        acc.z = fmaf(w0, v0.z, acc.z); acc.w = fmaf(w0, v0.w, acc.w);
        acc.x = fmaf(w1, v1.x, acc.x); acc.y = fmaf(w1, v1.y, acc.y);
        acc.z = fmaf(w1, v1.z, acc.z); acc.w = fmaf(w1, v1.w, acc.w);
        acc.x = fmaf(w2, v2.x, acc.x); acc.y = fmaf(w2, v2.y, acc.y);
        acc.z = fmaf(w2, v2.z, acc.z); acc.w = fmaf(w2, v2.w, acc.w);
        acc.x = fmaf(w3, v3.x, acc.x); acc.y = fmaf(w3, v3.y, acc.y);
        acc.z = fmaf(w3, v3.z, acc.z); acc.w = fmaf(w3, v3.w, acc.w);
        acc.x = fmaf(w4, v4.x, acc.x); acc.y = fmaf(w4, v4.y, acc.y);
        acc.z = fmaf(w4, v4.z, acc.z); acc.w = fmaf(w4, v4.w, acc.w);
        acc.x = fmaf(w5, v5.x, acc.x); acc.y = fmaf(w5, v5.y, acc.y);
        acc.z = fmaf(w5, v5.z, acc.z); acc.w = fmaf(w5, v5.w, acc.w);
        acc.x = fmaf(w6, v6.x, acc.x); acc.y = fmaf(w6, v6.y, acc.y);
        acc.z = fmaf(w6, v6.z, acc.z); acc.w = fmaf(w6, v6.w, acc.w);
        acc.x = fmaf(w7, v7.x, acc.x); acc.y = fmaf(w7, v7.y, acc.y);
        acc.z = fmaf(w7, v7.z, acc.z); acc.w = fmaf(w7, v7.w, acc.w);
    }
    for (; n < n1; n += 8) {
        float ww = w[n];
        float4 a = v[(size_t)n * 32 + fi];
        acc.x = fmaf(ww, a.x, acc.x);
        acc.y = fmaf(ww, a.y, acc.y);
        acc.z = fmaf(ww, a.z, acc.z);
        acc.w = fmaf(ww, a.w, acc.w);
    }
    __shared__ float4 part[256];
    part[tid] = acc;
    __syncthreads();
    if (tid < 32) {
        const float invZ = 1.f / Z[q];
        float4 a = part[tid];
        #pragma unroll
        for (int gg = 1; gg < 8; ++gg) {
            float4 b = part[gg * 32 + tid];
            a.x += b.x; a.y += b.y; a.z += b.z; a.w += b.w;
        }
        atomicAdd(&ctx[q * FIN + fi * 4 + 0], a.x * invZ);
        atomicAdd(&ctx[q * FIN + fi * 4 + 1], a.y * invZ);
        atomicAdd(&ctx[q * FIN + fi * 4 + 2], a.z * invZ);
        atomicAdd(&ctx[q * FIN + fi * 4 + 3], a.w * invZ);
    }
}

extern "C" void kernel_launch(void* const* d_in, const int* in_sizes, int n_in,
                              void* d_out, int out_size, void* d_ws, size_t ws_size,
                              hipStream_t stream) {
    const float* query  = (const float*)d_in[0];
    const float* values = (const float*)d_in[1];
    const int*   edges  = (const int*)d_in[2];
    const float* W1     = (const float*)d_in[3];
    const float* b1     = (const float*)d_in[4];
    const float* W2     = (const float*)d_in[5];
    const float* b2     = (const float*)d_in[6];

    const int N = in_sizes[2] / KN;           // 50000
    const int Q = in_sizes[0] / (N * FIN);    // 4

    float* out   = (float*)d_out;
    float* ctx   = out;                       // [Q,128]
    float* score = out + (size_t)Q * FIN;     // [Q,N]

    char* ws = (char*)d_ws;
    __half* y = (__half*)ws;                                    // [Q,N,64] f16
    size_t off = (size_t)Q * N * FOUT * sizeof(__half);
    float* s1  = (float*)(ws + off);  off += (size_t)Q * N * sizeof(float);
    float* wun = (float*)(ws + off);  off += (size_t)Q * N * sizeof(float);
    short* W1pk = (short*)(ws + off); off += (size_t)2 * 16 * 64 * 8 * sizeof(short);
    float* Z   = (float*)(ws + off);

    k_prep<<<1, 512, 0, stream>>>(W1, W1pk, Z, ctx, Q);
    dim3 g1((N + 255) / 256, Q);
    k_xw<<<g1, 256, 0, stream>>>(query, W1pk, y, N);
    dim3 g2((N + 3) / 4, Q);
    k_agg<<<g2, 256, 0, stream>>>(y, edges, b1, W2, s1, N);
    dim3 g3((N + 255) / 256, Q);
    k_score<<<g3, 256, 0, stream>>>(s1, edges, b2, score, wun, Z, N);
    dim3 g4(256, Q);
    k_context<<<g4, 256, 0, stream>>>(values, wun, Z, ctx, N);
}

// Round 5
// 140.254 us; speedup vs baseline: 1.2553x; 1.2553x over previous
//
#include <hip/hip_runtime.h>
#include <hip/hip_fp16.h>
#include <math.h>

// GraphAttention: Q=4, N=50000, K=8, F_IN=128, F_OUT=64
//   y  = query @ W1        (MFMA: A=bf16(query), B=W1 split hi+lo bf16; f16 out)
//   s1 = tanh(mean_k y[e]+b1) . W2
//   score = mean_k s1[e] + b2
//   softmax without max-sub (scores bounded ~|2|): w=exp(s)/Z
//   ctx = (sum_n exp(s_n) * values[n]) / Z   — two-phase partials, NO atomics

#define FIN 128
#define FOUT 64
#define KN 8
#define CTXB 256   // context phase-1 blocks per q

typedef short bf16x8 __attribute__((ext_vector_type(8)));
typedef float f32x4 __attribute__((ext_vector_type(4)));

__device__ inline short f2bf(float x) {
    unsigned u = __float_as_uint(x);
    unsigned r = (u + 0x7fffu + ((u >> 16) & 1u)) >> 16;
    return (short)r;
}
__device__ inline float bf2f(short s) {
    return __uint_as_float(((unsigned)(unsigned short)s) << 16);
}
__device__ inline unsigned pkadd(unsigned a, unsigned b) {
    __half2 ha = *(__half2*)&a, hb = *(__half2*)&b;
    __half2 r = __hadd2(ha, hb);
    return *(unsigned*)&r;
}

// ---------------- Stage 0: pack W1 (hi/lo bf16 MFMA B-frags); zero Z ----------------
__global__ __launch_bounds__(512) void k_prep(const float* __restrict__ W1,
                                              short* __restrict__ W1pk,
                                              float* __restrict__ Z, int Q) {
    const int tid = threadIdx.x;
    for (int it = 0; it < 2; ++it) {
        int p = tid + it * 512;
        int f = p >> 6, lane = p & 63;
        int kk = f >> 2, nt = f & 3;
        int lg = lane >> 4, lr = lane & 15;
        #pragma unroll
        for (int j = 0; j < 8; ++j) {
            float w = W1[(kk * 32 + lg * 8 + j) * FOUT + nt * 16 + lr];
            short h = f2bf(w);
            W1pk[(size_t)p * 8 + j] = h;                            // hi bank
            W1pk[1024 * 8 + (size_t)p * 8 + j] = f2bf(w - bf2f(h)); // lo bank
        }
    }
    if (tid < Q) Z[tid] = 0.f;
}

// ---------------- Stage 1: y = query @ W1 ----------------
// 4 waves/block, 2 tiles (32 nodes) per wave; ALL 16 A-loads hoisted (16KB/wave
// in flight), B-frags (L1-hot) reloaded per kk and shared by both tiles.
__global__ __launch_bounds__(256, 3) void k_xw(const float* __restrict__ query,
                                               const short* __restrict__ W1pk,
                                               __half* __restrict__ y, int N) {
    const int tid = threadIdx.x;
    const int wave = tid >> 6, lane = tid & 63;
    const int lg = lane >> 4, lr = lane & 15;
    const int q = blockIdx.y;
    const int base = blockIdx.x * 128 + wave * 32;
    const float* qb = query + (size_t)q * N * FIN;
    __half* yq = y + (size_t)q * N * FOUT;
    const bf16x8* Bp = (const bf16x8*)W1pk;   // [2][16][64] frags

    int n0 = base + lr;       if (n0 >= N) n0 = N - 1;
    int n1 = base + 16 + lr;  if (n1 >= N) n1 = N - 1;
    const float4* r0 = (const float4*)(qb + (size_t)n0 * FIN);
    const float4* r1 = (const float4*)(qb + (size_t)n1 * FIN);

    float4 a0[8], a1[8];
    #pragma unroll
    for (int kk = 0; kk < 4; ++kk) {
        a0[2 * kk]     = r0[kk * 8 + lg * 2];
        a0[2 * kk + 1] = r0[kk * 8 + lg * 2 + 1];
        a1[2 * kk]     = r1[kk * 8 + lg * 2];
        a1[2 * kk + 1] = r1[kk * 8 + lg * 2 + 1];
    }

    f32x4 acc0[4], acc1[4];
    #pragma unroll
    for (int nt = 0; nt < 4; ++nt) { acc0[nt] = (f32x4)0.f; acc1[nt] = (f32x4)0.f; }

    #pragma unroll
    for (int kk = 0; kk < 4; ++kk) {
        bf16x8 A0, A1;
        const float* x0 = (const float*)&a0[2 * kk];
        const float* x1 = (const float*)&a1[2 * kk];
        #pragma unroll
        for (int j = 0; j < 8; ++j) { A0[j] = f2bf(x0[j]); A1[j] = f2bf(x1[j]); }
        #pragma unroll
        for (int nt = 0; nt < 4; ++nt) {
            bf16x8 Bhi = Bp[(kk * 4 + nt) * 64 + lane];
            bf16x8 Blo = Bp[1024 + (kk * 4 + nt) * 64 + lane];
            acc0[nt] = __builtin_amdgcn_mfma_f32_16x16x32_bf16(A0, Bhi, acc0[nt], 0, 0, 0);
            acc0[nt] = __builtin_amdgcn_mfma_f32_16x16x32_bf16(A0, Blo, acc0[nt], 0, 0, 0);
            acc1[nt] = __builtin_amdgcn_mfma_f32_16x16x32_bf16(A1, Bhi, acc1[nt], 0, 0, 0);
            acc1[nt] = __builtin_amdgcn_mfma_f32_16x16x32_bf16(A1, Blo, acc1[nt], 0, 0, 0);
        }
    }
    #pragma unroll
    for (int r = 0; r < 4; ++r) {
        int m0 = base + lg * 4 + r;
        int m1 = base + 16 + lg * 4 + r;
        if (m0 < N) {
            #pragma unroll
            for (int nt = 0; nt < 4; ++nt)
                yq[(size_t)m0 * FOUT + nt * 16 + lr] = __float2half(acc0[nt][r]);
        }
        if (m1 < N) {
            #pragma unroll
            for (int nt = 0; nt < 4; ++nt)
                yq[(size_t)m1 * FOUT + nt * 16 + lr] = __float2half(acc1[nt][r]);
        }
    }
}

// ---------------- Stage 2: s1 = tanh(mean_k y[e]+b1).W2 — one node per wave ----------------
__global__ __launch_bounds__(256) void k_agg(const __half* __restrict__ y,
                                             const int* __restrict__ edges,
                                             const float* __restrict__ b1,
                                             const float* __restrict__ W2,
                                             float* __restrict__ s1, int N) {
    const int tid = threadIdx.x;
    const int wave = tid >> 6, lane = tid & 63;
    const int k = lane >> 3, c = lane & 7;
    const int n = blockIdx.x * 4 + wave;
    const int q = blockIdx.y;
    if (n >= N) return;
    const __half* yq = y + (size_t)q * N * FOUT;
    int e = edges[(size_t)n * KN + k];
    uint4 gv = *(const uint4*)(yq + (size_t)e * FOUT + c * 8);
    unsigned u0 = pkadd(gv.x, (unsigned)__shfl_xor((int)gv.x, 8));
    unsigned u1 = pkadd(gv.y, (unsigned)__shfl_xor((int)gv.y, 8));
    unsigned u2 = pkadd(gv.z, (unsigned)__shfl_xor((int)gv.z, 8));
    unsigned u3 = pkadd(gv.w, (unsigned)__shfl_xor((int)gv.w, 8));
    __half2 h0 = *(__half2*)&u0, h1 = *(__half2*)&u1, h2 = *(__half2*)&u2, h3 = *(__half2*)&u3;
    float f0 = __low2float(h0), f1 = __high2float(h0);
    float f2 = __low2float(h1), f3 = __high2float(h1);
    float f4 = __low2float(h2), f5 = __high2float(h2);
    float f6 = __low2float(h3), f7 = __high2float(h3);
    f0 += __shfl_xor(f0, 16); f1 += __shfl_xor(f1, 16);
    f2 += __shfl_xor(f2, 16); f3 += __shfl_xor(f3, 16);
    f4 += __shfl_xor(f4, 16); f5 += __shfl_xor(f5, 16);
    f6 += __shfl_xor(f6, 16); f7 += __shfl_xor(f7, 16);
    f0 += __shfl_xor(f0, 32); f1 += __shfl_xor(f1, 32);
    f2 += __shfl_xor(f2, 32); f3 += __shfl_xor(f3, 32);
    f4 += __shfl_xor(f4, 32); f5 += __shfl_xor(f5, 32);
    f6 += __shfl_xor(f6, 32); f7 += __shfl_xor(f7, 32);
    float e0 = (k & 1) ? f1 : f0;
    float e1 = (k & 1) ? f3 : f2;
    float e2 = (k & 1) ? f5 : f4;
    float e3 = (k & 1) ? f7 : f6;
    float e01 = (k & 2) ? e1 : e0;
    float e23 = (k & 2) ? e3 : e2;
    float sum = (k & 4) ? e23 : e01;
    const int f = c * 8 + k;
    float x = sum * 0.125f + b1[f];
    float ax = fabsf(x);
    float ee = __expf(-2.f * ax);
    float th = __fdividef(1.f - ee, 1.f + ee);
    th = copysignf(th, x);
    float p = th * W2[f];
    #pragma unroll
    for (int off = 32; off; off >>= 1) p += __shfl_xor(p, off);
    if (lane == 0) s1[(size_t)q * N + n] = p;
}

// ---------------- Stage 3: score = mean_k s1[e]+b2; w_un = exp(score); Z += Σ ----------------
__global__ __launch_bounds__(256) void k_score(const float* __restrict__ s1,
                                               const int* __restrict__ edges,
                                               const float* __restrict__ b2,
                                               float* __restrict__ score,
                                               float* __restrict__ wun,
                                               float* __restrict__ Z, int N) {
    const int n = blockIdx.x * 256 + threadIdx.x;
    const int q = blockIdx.y;
    const float* s1q = s1 + (size_t)q * N;
    float ex = 0.f;
    if (n < N) {
        float acc = 0.f;
        #pragma unroll
        for (int k = 0; k < KN; ++k) acc += s1q[edges[(size_t)n * KN + k]];
        float sc = acc * 0.125f + b2[0];
        score[(size_t)q * N + n] = sc;
        ex = expf(sc);
        wun[(size_t)q * N + n] = ex;
    }
    float p = ex;
    #pragma unroll
    for (int off = 32; off; off >>= 1) p += __shfl_xor(p, off);
    __shared__ float red[4];
    if ((threadIdx.x & 63) == 0) red[threadIdx.x >> 6] = p;
    __syncthreads();
    if (threadIdx.x == 0) atomicAdd(&Z[q], red[0] + red[1] + red[2] + red[3]);
}

// ---------------- Stage 4a: partial[q,cb,:] = Σ_chunk w_un * values — no atomics ----------------
__global__ __launch_bounds__(256) void k_context(const float* __restrict__ values,
                                                 const float* __restrict__ wun,
                                                 float* __restrict__ partial, int N) {
    const int q = blockIdx.y, cb = blockIdx.x;   // CTXB blocks per q
    const int tid = threadIdx.x;
    const int fi = tid & 31, g = tid >> 5;       // 8 node-groups x 32 float4-cols
    const float4* v = (const float4*)(values + (size_t)q * N * FIN);
    const float* w = wun + (size_t)q * N;
    const int chunk = (N + CTXB - 1) / CTXB;
    const int n0 = cb * chunk, n1 = min(n0 + chunk, N);
    float4 acc = make_float4(0.f, 0.f, 0.f, 0.f);
    int n = n0 + g;
    for (; n + 56 < n1; n += 64) {
        float w0 = w[n],      w1 = w[n + 8],  w2 = w[n + 16], w3 = w[n + 24];
        float w4 = w[n + 32], w5 = w[n + 40], w6 = w[n + 48], w7 = w[n + 56];
        float4 v0 = v[(size_t)n * 32 + fi];
        float4 v1 = v[(size_t)(n + 8) * 32 + fi];
        float4 v2 = v[(size_t)(n + 16) * 32 + fi];
        float4 v3 = v[(size_t)(n + 24) * 32 + fi];
        float4 v4 = v[(size_t)(n + 32) * 32 + fi];
        float4 v5 = v[(size_t)(n + 40) * 32 + fi];
        float4 v6 = v[(size_t)(n + 48) * 32 + fi];
        float4 v7 = v[(size_t)(n + 56) * 32 + fi];
        acc.x = fmaf(w0, v0.x, acc.x); acc.y = fmaf(w0, v0.y, acc.y);
        acc.z = fmaf(w0, v0.z, acc.z); acc.w = fmaf(w0, v0.w, acc.w);
        acc.x = fmaf(w1, v1.x, acc.x); acc.y = fmaf(w1, v1.y, acc.y);
        acc.z = fmaf(w1, v1.z, acc.z); acc.w = fmaf(w1, v1.w, acc.w);
        acc.x = fmaf(w2, v2.x, acc.x); acc.y = fmaf(w2, v2.y, acc.y);
        acc.z = fmaf(w2, v2.z, acc.z); acc.w = fmaf(w2, v2.w, acc.w);
        acc.x = fmaf(w3, v3.x, acc.x); acc.y = fmaf(w3, v3.y, acc.y);
        acc.z = fmaf(w3, v3.z, acc.z); acc.w = fmaf(w3, v3.w, acc.w);
        acc.x = fmaf(w4, v4.x, acc.x); acc.y = fmaf(w4, v4.y, acc.y);
        acc.z = fmaf(w4, v4.z, acc.z); acc.w = fmaf(w4, v4.w, acc.w);
        acc.x = fmaf(w5, v5.x, acc.x); acc.y = fmaf(w5, v5.y, acc.y);
        acc.z = fmaf(w5, v5.z, acc.z); acc.w = fmaf(w5, v5.w, acc.w);
        acc.x = fmaf(w6, v6.x, acc.x); acc.y = fmaf(w6, v6.y, acc.y);
        acc.z = fmaf(w6, v6.z, acc.z); acc.w = fmaf(w6, v6.w, acc.w);
        acc.x = fmaf(w7, v7.x, acc.x); acc.y = fmaf(w7, v7.y, acc.y);
        acc.z = fmaf(w7, v7.z, acc.z); acc.w = fmaf(w7, v7.w, acc.w);
    }
    for (; n < n1; n += 8) {
        float ww = w[n];
        float4 a = v[(size_t)n * 32 + fi];
        acc.x = fmaf(ww, a.x, acc.x);
        acc.y = fmaf(ww, a.y, acc.y);
        acc.z = fmaf(ww, a.z, acc.z);
        acc.w = fmaf(ww, a.w, acc.w);
    }
    __shared__ float4 part[256];
    part[tid] = acc;
    __syncthreads();
    if (tid < 32) {
        float4 a = part[tid];
        #pragma unroll
        for (int gg = 1; gg < 8; ++gg) {
            float4 b = part[gg * 32 + tid];
            a.x += b.x; a.y += b.y; a.z += b.z; a.w += b.w;
        }
        ((float4*)partial)[((size_t)q * CTXB + cb) * 32 + fi] = a;
    }
}

// ---------------- Stage 4b: ctx[q,f] = (Σ_cb partial[q,cb,f]) / Z[q] ----------------
__global__ __launch_bounds__(512) void k_final(const float* __restrict__ partial,
                                               const float* __restrict__ Z,
                                               float* __restrict__ ctx) {
    const int q = blockIdx.x;
    const int f = threadIdx.x & 127, h = threadIdx.x >> 7;   // 4 slices
    const float* p = partial + (size_t)q * CTXB * FIN;
    float s = 0.f;
    for (int b = h; b < CTXB; b += 4) s += p[(size_t)b * FIN + f];
    __shared__ float red[512];
    red[threadIdx.x] = s;
    __syncthreads();
    if (threadIdx.x < 128) {
        float t = red[threadIdx.x] + red[threadIdx.x + 128] +
                  red[threadIdx.x + 256] + red[threadIdx.x + 384];
        ctx[q * FIN + f] = t * (1.f / Z[q]);
    }
}

extern "C" void kernel_launch(void* const* d_in, const int* in_sizes, int n_in,
                              void* d_out, int out_size, void* d_ws, size_t ws_size,
                              hipStream_t stream) {
    const float* query  = (const float*)d_in[0];
    const float* values = (const float*)d_in[1];
    const int*   edges  = (const int*)d_in[2];
    const float* W1     = (const float*)d_in[3];
    const float* b1     = (const float*)d_in[4];
    const float* W2     = (const float*)d_in[5];
    const float* b2     = (const float*)d_in[6];

    const int N = in_sizes[2] / KN;           // 50000
    const int Q = in_sizes[0] / (N * FIN);    // 4

    float* out   = (float*)d_out;
    float* ctx   = out;                       // [Q,128]
    float* score = out + (size_t)Q * FIN;     // [Q,N]

    char* ws = (char*)d_ws;
    __half* y = (__half*)ws;                                    // [Q,N,64] f16
    size_t off = (size_t)Q * N * FOUT * sizeof(__half);
    float* s1   = (float*)(ws + off);  off += (size_t)Q * N * sizeof(float);
    float* wun  = (float*)(ws + off);  off += (size_t)Q * N * sizeof(float);
    short* W1pk = (short*)(ws + off);  off += (size_t)2 * 16 * 64 * 8 * sizeof(short);
    float* part = (float*)(ws + off);  off += (size_t)Q * CTXB * FIN * sizeof(float);
    float* Z    = (float*)(ws + off);                           // [Q]

    k_prep<<<1, 512, 0, stream>>>(W1, W1pk, Z, Q);
    dim3 g1((N + 127) / 128, Q);
    k_xw<<<g1, 256, 0, stream>>>(query, W1pk, y, N);
    dim3 g2((N + 3) / 4, Q);
    k_agg<<<g2, 256, 0, stream>>>(y, edges, b1, W2, s1, N);
    dim3 g3((N + 255) / 256, Q);
    k_score<<<g3, 256, 0, stream>>>(s1, edges, b2, score, wun, Z, N);
    dim3 g4(CTXB, Q);
    k_context<<<g4, 256, 0, stream>>>(values, wun, part, N);
    k_final<<<Q, 512, 0, stream>>>(part, Z, ctx);
}

// Round 6
// 110.510 us; speedup vs baseline: 1.5932x; 1.2692x over previous
//
#include <hip/hip_runtime.h>
#include <hip/hip_fp16.h>
#include <math.h>

// GraphAttention: Q=4, N=50000, K=8, F_IN=128, F_OUT=64
//   y  = query @ W1        (MFMA: A=bf16(query), B=W1 split hi+lo bf16; f16 out)
//   s1 = tanh(mean_k y[e]+b1) . W2
//   score = mean_k s1[e] + b2
//   softmax without max-sub (scores bounded ~|2|): w=exp(s)/Z
//   ctx = (sum_n exp(s_n) * values[n]) / Z   — two-phase partials, NO atomics

#define FIN 128
#define FOUT 64
#define KN 8
#define CTXB 256   // context phase-1 blocks per q

typedef short bf16x8 __attribute__((ext_vector_type(8)));
typedef float f32x4 __attribute__((ext_vector_type(4)));

__device__ inline short f2bf(float x) {
    unsigned u = __float_as_uint(x);
    unsigned r = (u + 0x7fffu + ((u >> 16) & 1u)) >> 16;
    return (short)r;
}
__device__ inline float bf2f(short s) {
    return __uint_as_float(((unsigned)(unsigned short)s) << 16);
}

// ---------------- Stage 0: pack W1 (hi/lo bf16 MFMA B-frags); zero Z ----------------
__global__ __launch_bounds__(512) void k_prep(const float* __restrict__ W1,
                                              short* __restrict__ W1pk,
                                              float* __restrict__ Z, int Q) {
    const int tid = threadIdx.x;
    for (int it = 0; it < 2; ++it) {
        int p = tid + it * 512;
        int f = p >> 6, lane = p & 63;
        int kk = f >> 2, nt = f & 3;
        int lg = lane >> 4, lr = lane & 15;
        #pragma unroll
        for (int j = 0; j < 8; ++j) {
            float w = W1[(kk * 32 + lg * 8 + j) * FOUT + nt * 16 + lr];
            short h = f2bf(w);
            W1pk[(size_t)p * 8 + j] = h;                            // hi bank
            W1pk[1024 * 8 + (size_t)p * 8 + j] = f2bf(w - bf2f(h)); // lo bank
        }
    }
    if (tid < Q) Z[tid] = 0.f;
}

// ---------------- Stage 1: y = query @ W1 ----------------
// 4 waves/block, 2 tiles (32 nodes) per wave; ALL 16 A-loads hoisted,
// B-frags (L1-hot) reloaded per kk and shared by both tiles.
__global__ __launch_bounds__(256, 3) void k_xw(const float* __restrict__ query,
                                               const short* __restrict__ W1pk,
                                               __half* __restrict__ y, int N) {
    const int tid = threadIdx.x;
    const int wave = tid >> 6, lane = tid & 63;
    const int lg = lane >> 4, lr = lane & 15;
    const int q = blockIdx.y;
    const int base = blockIdx.x * 128 + wave * 32;
    const float* qb = query + (size_t)q * N * FIN;
    __half* yq = y + (size_t)q * N * FOUT;
    const bf16x8* Bp = (const bf16x8*)W1pk;   // [2][16][64] frags

    int n0 = base + lr;       if (n0 >= N) n0 = N - 1;
    int n1 = base + 16 + lr;  if (n1 >= N) n1 = N - 1;
    const float4* r0 = (const float4*)(qb + (size_t)n0 * FIN);
    const float4* r1 = (const float4*)(qb + (size_t)n1 * FIN);

    float4 a0[8], a1[8];
    #pragma unroll
    for (int kk = 0; kk < 4; ++kk) {
        a0[2 * kk]     = r0[kk * 8 + lg * 2];
        a0[2 * kk + 1] = r0[kk * 8 + lg * 2 + 1];
        a1[2 * kk]     = r1[kk * 8 + lg * 2];
        a1[2 * kk + 1] = r1[kk * 8 + lg * 2 + 1];
    }

    f32x4 acc0[4], acc1[4];
    #pragma unroll
    for (int nt = 0; nt < 4; ++nt) { acc0[nt] = (f32x4)0.f; acc1[nt] = (f32x4)0.f; }

    #pragma unroll
    for (int kk = 0; kk < 4; ++kk) {
        bf16x8 A0, A1;
        const float* x0 = (const float*)&a0[2 * kk];
        const float* x1 = (const float*)&a1[2 * kk];
        #pragma unroll
        for (int j = 0; j < 8; ++j) { A0[j] = f2bf(x0[j]); A1[j] = f2bf(x1[j]); }
        #pragma unroll
        for (int nt = 0; nt < 4; ++nt) {
            bf16x8 Bhi = Bp[(kk * 4 + nt) * 64 + lane];
            bf16x8 Blo = Bp[1024 + (kk * 4 + nt) * 64 + lane];
            acc0[nt] = __builtin_amdgcn_mfma_f32_16x16x32_bf16(A0, Bhi, acc0[nt], 0, 0, 0);
            acc0[nt] = __builtin_amdgcn_mfma_f32_16x16x32_bf16(A0, Blo, acc0[nt], 0, 0, 0);
            acc1[nt] = __builtin_amdgcn_mfma_f32_16x16x32_bf16(A1, Bhi, acc1[nt], 0, 0, 0);
            acc1[nt] = __builtin_amdgcn_mfma_f32_16x16x32_bf16(A1, Blo, acc1[nt], 0, 0, 0);
        }
    }
    #pragma unroll
    for (int r = 0; r < 4; ++r) {
        int m0 = base + lg * 4 + r;
        int m1 = base + 16 + lg * 4 + r;
        if (m0 < N) {
            #pragma unroll
            for (int nt = 0; nt < 4; ++nt)
                yq[(size_t)m0 * FOUT + nt * 16 + lr] = __float2half(acc0[nt][r]);
        }
        if (m1 < N) {
            #pragma unroll
            for (int nt = 0; nt < 4; ++nt)
                yq[(size_t)m1 * FOUT + nt * 16 + lr] = __float2half(acc1[nt][r]);
        }
    }
}

// ---------------- Stage 2: s1 = tanh(mean_k y[e]+b1).W2 ----------------
// 2 nodes/wave, lane = feature-pair. Edge row loaded as broadcast int4 x2
// (no shuffles); all 8 half2 gathers issued up front; 7 packed hadd2; one
// 5-step shfl reduce. DS ops: 5/wave (was ~26).
__global__ __launch_bounds__(256) void k_agg(const __half* __restrict__ y,
                                             const int* __restrict__ edges,
                                             const float* __restrict__ b1,
                                             const float* __restrict__ W2,
                                             float* __restrict__ s1, int N) {
    const int tid = threadIdx.x;
    const int wave = tid >> 6, lane = tid & 63;
    const int half = lane >> 5, fl = lane & 31;
    const int q = blockIdx.y;
    const int n = blockIdx.x * 8 + wave * 2 + half;
    const int nc = n < N ? n : N - 1;
    const __half* yq = y + (size_t)q * N * FOUT;

    const int4* erow = (const int4*)(edges + (size_t)nc * KN);
    int4 ea = erow[0], eb = erow[1];           // broadcast within node-half

    const __half2* y2 = (const __half2*)yq;
    __half2 v0 = y2[(size_t)ea.x * 32 + fl];
    __half2 v1 = y2[(size_t)ea.y * 32 + fl];
    __half2 v2 = y2[(size_t)ea.z * 32 + fl];
    __half2 v3 = y2[(size_t)ea.w * 32 + fl];
    __half2 v4 = y2[(size_t)eb.x * 32 + fl];
    __half2 v5 = y2[(size_t)eb.y * 32 + fl];
    __half2 v6 = y2[(size_t)eb.z * 32 + fl];
    __half2 v7 = y2[(size_t)eb.w * 32 + fl];

    __half2 s01 = __hadd2(v0, v1), s23 = __hadd2(v2, v3);
    __half2 s45 = __hadd2(v4, v5), s67 = __hadd2(v6, v7);
    __half2 sum = __hadd2(__hadd2(s01, s23), __hadd2(s45, s67));
    float2 sf = __half22float2(sum);

    float2 bv = *(const float2*)(b1 + fl * 2);
    float2 wv = *(const float2*)(W2 + fl * 2);
    float x0 = sf.x * 0.125f + bv.x;
    float x1 = sf.y * 0.125f + bv.y;
    float a0 = fabsf(x0), a1 = fabsf(x1);
    float e0 = __expf(-2.f * a0), e1 = __expf(-2.f * a1);
    float t0 = __fdividef(1.f - e0, 1.f + e0);
    float t1 = __fdividef(1.f - e1, 1.f + e1);
    t0 = copysignf(t0, x0);
    t1 = copysignf(t1, x1);
    float p = t0 * wv.x + t1 * wv.y;
    #pragma unroll
    for (int off = 16; off; off >>= 1) p += __shfl_xor(p, off);
    if (fl == 0 && n < N) s1[(size_t)q * N + n] = p;
}

// ---------------- Stage 3: score = mean_k s1[e]+b2; w_un = exp(score); Z += Σ ----------------
__global__ __launch_bounds__(256) void k_score(const float* __restrict__ s1,
                                               const int* __restrict__ edges,
                                               const float* __restrict__ b2,
                                               float* __restrict__ score,
                                               float* __restrict__ wun,
                                               float* __restrict__ Z, int N) {
    const int n = blockIdx.x * 256 + threadIdx.x;
    const int q = blockIdx.y;
    const float* s1q = s1 + (size_t)q * N;
    float ex = 0.f;
    if (n < N) {
        float acc = 0.f;
        #pragma unroll
        for (int k = 0; k < KN; ++k) acc += s1q[edges[(size_t)n * KN + k]];
        float sc = acc * 0.125f + b2[0];
        score[(size_t)q * N + n] = sc;
        ex = expf(sc);
        wun[(size_t)q * N + n] = ex;
    }
    float p = ex;
    #pragma unroll
    for (int off = 32; off; off >>= 1) p += __shfl_xor(p, off);
    __shared__ float red[4];
    if ((threadIdx.x & 63) == 0) red[threadIdx.x >> 6] = p;
    __syncthreads();
    if (threadIdx.x == 0) atomicAdd(&Z[q], red[0] + red[1] + red[2] + red[3]);
}

// ---------------- Stage 4a: partial[q,cb,:] = Σ_chunk w_un * values — no atomics ----------------
__global__ __launch_bounds__(256) void k_context(const float* __restrict__ values,
                                                 const float* __restrict__ wun,
                                                 float* __restrict__ partial, int N) {
    const int q = blockIdx.y, cb = blockIdx.x;   // CTXB blocks per q
    const int tid = threadIdx.x;
    const int fi = tid & 31, g = tid >> 5;       // 8 node-groups x 32 float4-cols
    const float4* v = (const float4*)(values + (size_t)q * N * FIN);
    const float* w = wun + (size_t)q * N;
    const int chunk = (N + CTXB - 1) / CTXB;
    const int n0 = cb * chunk, n1 = min(n0 + chunk, N);
    float4 acc = make_float4(0.f, 0.f, 0.f, 0.f);
    int n = n0 + g;
    for (; n + 56 < n1; n += 64) {
        float w0 = w[n],      w1 = w[n + 8],  w2 = w[n + 16], w3 = w[n + 24];
        float w4 = w[n + 32], w5 = w[n + 40], w6 = w[n + 48], w7 = w[n + 56];
        float4 v0 = v[(size_t)n * 32 + fi];
        float4 v1 = v[(size_t)(n + 8) * 32 + fi];
        float4 v2 = v[(size_t)(n + 16) * 32 + fi];
        float4 v3 = v[(size_t)(n + 24) * 32 + fi];
        float4 v4 = v[(size_t)(n + 32) * 32 + fi];
        float4 v5 = v[(size_t)(n + 40) * 32 + fi];
        float4 v6 = v[(size_t)(n + 48) * 32 + fi];
        float4 v7 = v[(size_t)(n + 56) * 32 + fi];
        acc.x = fmaf(w0, v0.x, acc.x); acc.y = fmaf(w0, v0.y, acc.y);
        acc.z = fmaf(w0, v0.z, acc.z); acc.w = fmaf(w0, v0.w, acc.w);
        acc.x = fmaf(w1, v1.x, acc.x); acc.y = fmaf(w1, v1.y, acc.y);
        acc.z = fmaf(w1, v1.z, acc.z); acc.w = fmaf(w1, v1.w, acc.w);
        acc.x = fmaf(w2, v2.x, acc.x); acc.y = fmaf(w2, v2.y, acc.y);
        acc.z = fmaf(w2, v2.z, acc.z); acc.w = fmaf(w2, v2.w, acc.w);
        acc.x = fmaf(w3, v3.x, acc.x); acc.y = fmaf(w3, v3.y, acc.y);
        acc.z = fmaf(w3, v3.z, acc.z); acc.w = fmaf(w3, v3.w, acc.w);
        acc.x = fmaf(w4, v4.x, acc.x); acc.y = fmaf(w4, v4.y, acc.y);
        acc.z = fmaf(w4, v4.z, acc.z); acc.w = fmaf(w4, v4.w, acc.w);
        acc.x = fmaf(w5, v5.x, acc.x); acc.y = fmaf(w5, v5.y, acc.y);
        acc.z = fmaf(w5, v5.z, acc.z); acc.w = fmaf(w5, v5.w, acc.w);
        acc.x = fmaf(w6, v6.x, acc.x); acc.y = fmaf(w6, v6.y, acc.y);
        acc.z = fmaf(w6, v6.z, acc.z); acc.w = fmaf(w6, v6.w, acc.w);
        acc.x = fmaf(w7, v7.x, acc.x); acc.y = fmaf(w7, v7.y, acc.y);
        acc.z = fmaf(w7, v7.z, acc.z); acc.w = fmaf(w7, v7.w, acc.w);
    }
    for (; n < n1; n += 8) {
        float ww = w[n];
        float4 a = v[(size_t)n * 32 + fi];
        acc.x = fmaf(ww, a.x, acc.x);
        acc.y = fmaf(ww, a.y, acc.y);
        acc.z = fmaf(ww, a.z, acc.z);
        acc.w = fmaf(ww, a.w, acc.w);
    }
    __shared__ float4 part[256];
    part[tid] = acc;
    __syncthreads();
    if (tid < 32) {
        float4 a = part[tid];
        #pragma unroll
        for (int gg = 1; gg < 8; ++gg) {
            float4 b = part[gg * 32 + tid];
            a.x += b.x; a.y += b.y; a.z += b.z; a.w += b.w;
        }
        ((float4*)partial)[((size_t)q * CTXB + cb) * 32 + fi] = a;
    }
}

// ---------------- Stage 4b: ctx[q,f] = (Σ_cb partial[q,cb,f]) / Z[q] ----------------
__global__ __launch_bounds__(512) void k_final(const float* __restrict__ partial,
                                               const float* __restrict__ Z,
                                               float* __restrict__ ctx) {
    const int q = blockIdx.x;
    const int f = threadIdx.x & 127, h = threadIdx.x >> 7;   // 4 slices
    const float* p = partial + (size_t)q * CTXB * FIN;
    float s = 0.f;
    for (int b = h; b < CTXB; b += 4) s += p[(size_t)b * FIN + f];
    __shared__ float red[512];
    red[threadIdx.x] = s;
    __syncthreads();
    if (threadIdx.x < 128) {
        float t = red[threadIdx.x] + red[threadIdx.x + 128] +
                  red[threadIdx.x + 256] + red[threadIdx.x + 384];
        ctx[q * FIN + f] = t * (1.f / Z[q]);
    }
}

extern "C" void kernel_launch(void* const* d_in, const int* in_sizes, int n_in,
                              void* d_out, int out_size, void* d_ws, size_t ws_size,
                              hipStream_t stream) {
    const float* query  = (const float*)d_in[0];
    const float* values = (const float*)d_in[1];
    const int*   edges  = (const int*)d_in[2];
    const float* W1     = (const float*)d_in[3];
    const float* b1     = (const float*)d_in[4];
    const float* W2     = (const float*)d_in[5];
    const float* b2     = (const float*)d_in[6];

    const int N = in_sizes[2] / KN;           // 50000
    const int Q = in_sizes[0] / (N * FIN);    // 4

    float* out   = (float*)d_out;
    float* ctx   = out;                       // [Q,128]
    float* score = out + (size_t)Q * FIN;     // [Q,N]

    char* ws = (char*)d_ws;
    __half* y = (__half*)ws;                                    // [Q,N,64] f16
    size_t off = (size_t)Q * N * FOUT * sizeof(__half);
    float* s1   = (float*)(ws + off);  off += (size_t)Q * N * sizeof(float);
    float* wun  = (float*)(ws + off);  off += (size_t)Q * N * sizeof(float);
    short* W1pk = (short*)(ws + off);  off += (size_t)2 * 16 * 64 * 8 * sizeof(short);
    float* part = (float*)(ws + off);  off += (size_t)Q * CTXB * FIN * sizeof(float);
    float* Z    = (float*)(ws + off);                           // [Q]

    k_prep<<<1, 512, 0, stream>>>(W1, W1pk, Z, Q);
    dim3 g1((N + 127) / 128, Q);
    k_xw<<<g1, 256, 0, stream>>>(query, W1pk, y, N);
    dim3 g2((N + 7) / 8, Q);
    k_agg<<<g2, 256, 0, stream>>>(y, edges, b1, W2, s1, N);
    dim3 g3((N + 255) / 256, Q);
    k_score<<<g3, 256, 0, stream>>>(s1, edges, b2, score, wun, Z, N);
    dim3 g4(CTXB, Q);
    k_context<<<g4, 256, 0, stream>>>(values, wun, part, N);
    k_final<<<Q, 512, 0, stream>>>(part, Z, ctx);
}

// Round 7
// 92.420 us; speedup vs baseline: 1.9051x; 1.1957x over previous
//
#include <hip/hip_runtime.h>
#include <hip/hip_fp16.h>
#include <math.h>

// GraphAttention: Q=4, N=50000, K=8, F_IN=128, F_OUT=64
//   y  = query @ W1        (MFMA: A=bf16(query), B=W1 split hi+lo bf16; f16 out)
//   s1 = tanh(mean_k y[e]+b1) . W2
//   score = mean_k s1[e] + b2
//   softmax without max-sub (scores bounded ~|2|): w=exp(s)/Z
//   ctx = (sum_n exp(s_n) * values[n]) / Z
// 4 launches: k_xw (self-packs W1), k_agg, k_ctx (score+exp+weighted sum fused),
// k_final (reduce partials + Z). No atomics, no buffer pre-zeroing needed.

#define FIN 128
#define FOUT 64
#define KN 8
#define CTXB 256   // context blocks per q

typedef short bf16x8 __attribute__((ext_vector_type(8)));
typedef float f32x4 __attribute__((ext_vector_type(4)));

__device__ inline short f2bf(float x) {
    unsigned u = __float_as_uint(x);
    unsigned r = (u + 0x7fffu + ((u >> 16) & 1u)) >> 16;
    return (short)r;
}
__device__ inline float bf2f(short s) {
    return __uint_as_float(((unsigned)(unsigned short)s) << 16);
}

// ---------------- Stage 1: y = query @ W1 ----------------
// Each block packs W1 into LDS as hi/lo bf16 MFMA B-fragments (32 KB), then
// 4 waves x 2 tiles (32 nodes)/wave; all 16 A-loads hoisted; B-frags from LDS.
__global__ __launch_bounds__(256, 3) void k_xw(const float* __restrict__ query,
                                               const float* __restrict__ W1,
                                               __half* __restrict__ y, int N) {
    __shared__ short Wlds[2 * 8192];   // [2 banks][16 frags][64 lanes][8 shorts]
    const int tid = threadIdx.x;
    // ---- pack W1 -> LDS (coalesced global float4 reads, scattered b16 writes)
    const float4* W1v = (const float4*)W1;   // 2048 float4s
    #pragma unroll
    for (int it = 0; it < 8; ++it) {
        int vi = it * 256 + tid;
        float4 w4 = W1v[vi];
        float ws[4] = {w4.x, w4.y, w4.z, w4.w};
        #pragma unroll
        for (int c = 0; c < 4; ++c) {
            int gi = vi * 4 + c;
            int k = gi >> 6, f = gi & 63;           // W1[k][f]
            int kk = k >> 5, rem = k & 31, lg = rem >> 3, j = rem & 7;
            int nt = f >> 4, lr = f & 15;
            int p = (kk * 4 + nt) * 64 + lg * 16 + lr;
            short hi = f2bf(ws[c]);
            Wlds[p * 8 + j] = hi;
            Wlds[8192 + p * 8 + j] = f2bf(ws[c] - bf2f(hi));
        }
    }
    __syncthreads();

    const int wave = tid >> 6, lane = tid & 63;
    const int lg = lane >> 4, lr = lane & 15;
    const int q = blockIdx.y;
    const int base = blockIdx.x * 128 + wave * 32;
    const float* qb = query + (size_t)q * N * FIN;
    __half* yq = y + (size_t)q * N * FOUT;
    const bf16x8* Bp = (const bf16x8*)Wlds;

    int n0 = base + lr;       if (n0 >= N) n0 = N - 1;
    int n1 = base + 16 + lr;  if (n1 >= N) n1 = N - 1;
    const float4* r0 = (const float4*)(qb + (size_t)n0 * FIN);
    const float4* r1 = (const float4*)(qb + (size_t)n1 * FIN);

    float4 a0[8], a1[8];
    #pragma unroll
    for (int kk = 0; kk < 4; ++kk) {
        a0[2 * kk]     = r0[kk * 8 + lg * 2];
        a0[2 * kk + 1] = r0[kk * 8 + lg * 2 + 1];
        a1[2 * kk]     = r1[kk * 8 + lg * 2];
        a1[2 * kk + 1] = r1[kk * 8 + lg * 2 + 1];
    }

    f32x4 acc0[4], acc1[4];
    #pragma unroll
    for (int nt = 0; nt < 4; ++nt) { acc0[nt] = (f32x4)0.f; acc1[nt] = (f32x4)0.f; }

    #pragma unroll
    for (int kk = 0; kk < 4; ++kk) {
        bf16x8 A0, A1;
        const float* x0 = (const float*)&a0[2 * kk];
        const float* x1 = (const float*)&a1[2 * kk];
        #pragma unroll
        for (int j = 0; j < 8; ++j) { A0[j] = f2bf(x0[j]); A1[j] = f2bf(x1[j]); }
        #pragma unroll
        for (int nt = 0; nt < 4; ++nt) {
            bf16x8 Bhi = Bp[(kk * 4 + nt) * 64 + lane];
            bf16x8 Blo = Bp[1024 + (kk * 4 + nt) * 64 + lane];
            acc0[nt] = __builtin_amdgcn_mfma_f32_16x16x32_bf16(A0, Bhi, acc0[nt], 0, 0, 0);
            acc0[nt] = __builtin_amdgcn_mfma_f32_16x16x32_bf16(A0, Blo, acc0[nt], 0, 0, 0);
            acc1[nt] = __builtin_amdgcn_mfma_f32_16x16x32_bf16(A1, Bhi, acc1[nt], 0, 0, 0);
            acc1[nt] = __builtin_amdgcn_mfma_f32_16x16x32_bf16(A1, Blo, acc1[nt], 0, 0, 0);
        }
    }
    #pragma unroll
    for (int r = 0; r < 4; ++r) {
        int m0 = base + lg * 4 + r;
        int m1 = base + 16 + lg * 4 + r;
        if (m0 < N) {
            #pragma unroll
            for (int nt = 0; nt < 4; ++nt)
                yq[(size_t)m0 * FOUT + nt * 16 + lr] = __float2half(acc0[nt][r]);
        }
        if (m1 < N) {
            #pragma unroll
            for (int nt = 0; nt < 4; ++nt)
                yq[(size_t)m1 * FOUT + nt * 16 + lr] = __float2half(acc1[nt][r]);
        }
    }
}

// ---------------- Stage 2: s1 = tanh(mean_k y[e]+b1).W2 ----------------
// 2 nodes/wave, lane = feature-pair; 8 independent coalesced row gathers.
__global__ __launch_bounds__(256) void k_agg(const __half* __restrict__ y,
                                             const int* __restrict__ edges,
                                             const float* __restrict__ b1,
                                             const float* __restrict__ W2,
                                             float* __restrict__ s1, int N) {
    const int tid = threadIdx.x;
    const int wave = tid >> 6, lane = tid & 63;
    const int half = lane >> 5, fl = lane & 31;
    const int q = blockIdx.y;
    const int n = blockIdx.x * 8 + wave * 2 + half;
    const int nc = n < N ? n : N - 1;
    const __half* yq = y + (size_t)q * N * FOUT;

    const int4* erow = (const int4*)(edges + (size_t)nc * KN);
    int4 ea = erow[0], eb = erow[1];

    const __half2* y2 = (const __half2*)yq;
    __half2 v0 = y2[(size_t)ea.x * 32 + fl];
    __half2 v1 = y2[(size_t)ea.y * 32 + fl];
    __half2 v2 = y2[(size_t)ea.z * 32 + fl];
    __half2 v3 = y2[(size_t)ea.w * 32 + fl];
    __half2 v4 = y2[(size_t)eb.x * 32 + fl];
    __half2 v5 = y2[(size_t)eb.y * 32 + fl];
    __half2 v6 = y2[(size_t)eb.z * 32 + fl];
    __half2 v7 = y2[(size_t)eb.w * 32 + fl];

    __half2 s01 = __hadd2(v0, v1), s23 = __hadd2(v2, v3);
    __half2 s45 = __hadd2(v4, v5), s67 = __hadd2(v6, v7);
    __half2 sum = __hadd2(__hadd2(s01, s23), __hadd2(s45, s67));
    float2 sf = __half22float2(sum);

    float2 bv = *(const float2*)(b1 + fl * 2);
    float2 wv = *(const float2*)(W2 + fl * 2);
    float x0 = sf.x * 0.125f + bv.x;
    float x1 = sf.y * 0.125f + bv.y;
    float a0 = fabsf(x0), a1 = fabsf(x1);
    float e0 = __expf(-2.f * a0), e1 = __expf(-2.f * a1);
    float t0 = __fdividef(1.f - e0, 1.f + e0);
    float t1 = __fdividef(1.f - e1, 1.f + e1);
    t0 = copysignf(t0, x0);
    t1 = copysignf(t1, x1);
    float p = t0 * wv.x + t1 * wv.y;
    #pragma unroll
    for (int off = 16; off; off >>= 1) p += __shfl_xor(p, off);
    if (fl == 0 && n < N) s1[(size_t)q * N + n] = p;
}

// ---------------- Stage 3 (fused): score + exp + Z-partial + weighted values ----------------
__global__ __launch_bounds__(256) void k_ctx(const float* __restrict__ values,
                                             const float* __restrict__ s1,
                                             const int* __restrict__ edges,
                                             const float* __restrict__ b2,
                                             float* __restrict__ score,
                                             float* __restrict__ partial,
                                             float* __restrict__ zpart, int N) {
    const int q = blockIdx.y, cb = blockIdx.x;
    const int tid = threadIdx.x;
    const int chunk = (N + CTXB - 1) / CTXB;
    const int n0 = cb * chunk, n1 = min(n0 + chunk, N);
    const int cnt = n1 - n0;
    __shared__ float wlds[512];
    __shared__ float zred[4];
    const float* s1q = s1 + (size_t)q * N;
    const float b2v = b2[0];

    // phase 1: scores + exp for this chunk
    float zp = 0.f;
    for (int t = tid; t < cnt; t += 256) {
        int n = n0 + t;
        float acc = 0.f;
        #pragma unroll
        for (int k = 0; k < KN; ++k) acc += s1q[edges[(size_t)n * KN + k]];
        float sc = acc * 0.125f + b2v;
        score[(size_t)q * N + n] = sc;
        float ex = __expf(sc);
        wlds[t] = ex;
        zp += ex;
    }
    float z = zp;
    #pragma unroll
    for (int off = 32; off; off >>= 1) z += __shfl_xor(z, off);
    if ((tid & 63) == 0) zred[tid >> 6] = z;
    __syncthreads();

    // phase 2: weighted values stream (unroll-8, independent loads)
    const int fi = tid & 31, g = tid >> 5;
    const float4* v = (const float4*)(values + (size_t)q * N * FIN);
    float4 acc = make_float4(0.f, 0.f, 0.f, 0.f);
    int n = n0 + g;
    for (; n + 56 < n1; n += 64) {
        int l = n - n0;
        float w0 = wlds[l],      w1 = wlds[l + 8],  w2 = wlds[l + 16], w3 = wlds[l + 24];
        float w4 = wlds[l + 32], w5 = wlds[l + 40], w6 = wlds[l + 48], w7 = wlds[l + 56];
        float4 v0 = v[(size_t)n * 32 + fi];
        float4 v1 = v[(size_t)(n + 8) * 32 + fi];
        float4 v2 = v[(size_t)(n + 16) * 32 + fi];
        float4 v3 = v[(size_t)(n + 24) * 32 + fi];
        float4 v4 = v[(size_t)(n + 32) * 32 + fi];
        float4 v5 = v[(size_t)(n + 40) * 32 + fi];
        float4 v6 = v[(size_t)(n + 48) * 32 + fi];
        float4 v7 = v[(size_t)(n + 56) * 32 + fi];
        acc.x = fmaf(w0, v0.x, acc.x); acc.y = fmaf(w0, v0.y, acc.y);
        acc.z = fmaf(w0, v0.z, acc.z); acc.w = fmaf(w0, v0.w, acc.w);
        acc.x = fmaf(w1, v1.x, acc.x); acc.y = fmaf(w1, v1.y, acc.y);
        acc.z = fmaf(w1, v1.z, acc.z); acc.w = fmaf(w1, v1.w, acc.w);
        acc.x = fmaf(w2, v2.x, acc.x); acc.y = fmaf(w2, v2.y, acc.y);
        acc.z = fmaf(w2, v2.z, acc.z); acc.w = fmaf(w2, v2.w, acc.w);
        acc.x = fmaf(w3, v3.x, acc.x); acc.y = fmaf(w3, v3.y, acc.y);
        acc.z = fmaf(w3, v3.z, acc.z); acc.w = fmaf(w3, v3.w, acc.w);
        acc.x = fmaf(w4, v4.x, acc.x); acc.y = fmaf(w4, v4.y, acc.y);
        acc.z = fmaf(w4, v4.z, acc.z); acc.w = fmaf(w4, v4.w, acc.w);
        acc.x = fmaf(w5, v5.x, acc.x); acc.y = fmaf(w5, v5.y, acc.y);
        acc.z = fmaf(w5, v5.z, acc.z); acc.w = fmaf(w5, v5.w, acc.w);
        acc.x = fmaf(w6, v6.x, acc.x); acc.y = fmaf(w6, v6.y, acc.y);
        acc.z = fmaf(w6, v6.z, acc.z); acc.w = fmaf(w6, v6.w, acc.w);
        acc.x = fmaf(w7, v7.x, acc.x); acc.y = fmaf(w7, v7.y, acc.y);
        acc.z = fmaf(w7, v7.z, acc.z); acc.w = fmaf(w7, v7.w, acc.w);
    }
    for (; n < n1; n += 8) {
        float ww = wlds[n - n0];
        float4 a = v[(size_t)n * 32 + fi];
        acc.x = fmaf(ww, a.x, acc.x);
        acc.y = fmaf(ww, a.y, acc.y);
        acc.z = fmaf(ww, a.z, acc.z);
        acc.w = fmaf(ww, a.w, acc.w);
    }
    __shared__ float4 part[256];
    part[tid] = acc;
    __syncthreads();
    if (tid < 32) {
        float4 a = part[tid];
        #pragma unroll
        for (int gg = 1; gg < 8; ++gg) {
            float4 b = part[gg * 32 + tid];
            a.x += b.x; a.y += b.y; a.z += b.z; a.w += b.w;
        }
        ((float4*)partial)[((size_t)q * CTXB + cb) * 32 + fi] = a;
    }
    if (tid == 0) zpart[(size_t)q * CTXB + cb] = zred[0] + zred[1] + zred[2] + zred[3];
}

// ---------------- Stage 4: ctx[q,f] = (Σ_cb partial[q,cb,f]) / (Σ_cb zpart[q,cb]) ----------------
__global__ __launch_bounds__(512) void k_final(const float* __restrict__ partial,
                                               const float* __restrict__ zpart,
                                               float* __restrict__ ctx) {
    const int q = blockIdx.x;
    const int tid = threadIdx.x;
    const int f = tid & 127, h = tid >> 7;
    const float* p = partial + (size_t)q * CTXB * FIN;
    float s = 0.f;
    for (int b = h; b < CTXB; b += 4) s += p[(size_t)b * FIN + f];
    __shared__ float red[512];
    __shared__ float zred[8];
    red[tid] = s;
    float z = (tid < CTXB) ? zpart[(size_t)q * CTXB + tid] : 0.f;
    #pragma unroll
    for (int off = 32; off; off >>= 1) z += __shfl_xor(z, off);
    if ((tid & 63) == 0) zred[tid >> 6] = z;
    __syncthreads();
    if (tid < 128) {
        float Zt = zred[0] + zred[1] + zred[2] + zred[3] +
                   zred[4] + zred[5] + zred[6] + zred[7];
        float t = red[tid] + red[tid + 128] + red[tid + 256] + red[tid + 384];
        ctx[q * FIN + f] = t * (1.f / Zt);
    }
}

extern "C" void kernel_launch(void* const* d_in, const int* in_sizes, int n_in,
                              void* d_out, int out_size, void* d_ws, size_t ws_size,
                              hipStream_t stream) {
    const float* query  = (const float*)d_in[0];
    const float* values = (const float*)d_in[1];
    const int*   edges  = (const int*)d_in[2];
    const float* W1     = (const float*)d_in[3];
    const float* b1     = (const float*)d_in[4];
    const float* W2     = (const float*)d_in[5];
    const float* b2     = (const float*)d_in[6];

    const int N = in_sizes[2] / KN;           // 50000
    const int Q = in_sizes[0] / (N * FIN);    // 4

    float* out   = (float*)d_out;
    float* ctx   = out;                       // [Q,128]
    float* score = out + (size_t)Q * FIN;     // [Q,N]

    char* ws = (char*)d_ws;
    __half* y = (__half*)ws;                                    // [Q,N,64] f16
    size_t off = (size_t)Q * N * FOUT * sizeof(__half);
    float* s1    = (float*)(ws + off);  off += (size_t)Q * N * sizeof(float);
    float* part  = (float*)(ws + off);  off += (size_t)Q * CTXB * FIN * sizeof(float);
    float* zpart = (float*)(ws + off);                          // [Q,CTXB]

    dim3 g1((N + 127) / 128, Q);
    k_xw<<<g1, 256, 0, stream>>>(query, W1, y, N);
    dim3 g2((N + 7) / 8, Q);
    k_agg<<<g2, 256, 0, stream>>>(y, edges, b1, W2, s1, N);
    dim3 g3(CTXB, Q);
    k_ctx<<<g3, 256, 0, stream>>>(values, s1, edges, b2, score, part, zpart, N);
    k_final<<<Q, 512, 0, stream>>>(part, zpart, ctx);
}

// Round 9
// 90.781 us; speedup vs baseline: 1.9395x; 1.0181x over previous
//
#include <hip/hip_runtime.h>
#include <hip/hip_fp16.h>
#include <math.h>

// GraphAttention: Q=4, N=50000, K=8, F_IN=128, F_OUT=64
//   y  = query @ W1        (MFMA: A=bf16(query), B=W1 split hi+lo bf16; f16 out)
//   s1 = tanh(mean_k y[e]+b1) . W2
//   score = mean_k s1[e] + b2
//   softmax without max-sub (scores bounded ~|2|): w=exp(s)/Z
//   ctx = (sum_n exp(s_n) * values[n]) / Z
// 4 launches: k_xw (self-packs W1, conflict-free b128 pack), k_agg,
// k_ctx (score+exp+weighted sum fused), k_final.

#define FIN 128
#define FOUT 64
#define KN 8
#define CTXB 250   // context blocks per q -> chunk = exactly 200 nodes

typedef short bf16x8 __attribute__((ext_vector_type(8)));
typedef float f32x4 __attribute__((ext_vector_type(4)));

__device__ inline short f2bf(float x) {
    unsigned u = __float_as_uint(x);
    unsigned r = (u + 0x7fffu + ((u >> 16) & 1u)) >> 16;
    return (short)r;
}
__device__ inline float bf2f(short s) {
    return __uint_as_float(((unsigned)(unsigned short)s) << 16);
}

// ---------------- Stage 1: y = query @ W1 ----------------
// Pack: 1024 fragment rows (16 groups x 64 lanes); each thread builds 4 whole
// fragment-pairs in regs (8 column-strided reads of L2-hot W1 each), stores
// with conflict-free ds_write_b128.
__global__ __launch_bounds__(256, 3) void k_xw(const float* __restrict__ query,
                                               const float* __restrict__ W1,
                                               __half* __restrict__ y, int N) {
    __shared__ short Wlds[2 * 8192];   // [2 banks][16 frags][64 lanes][8 shorts]
    const int tid = threadIdx.x;
    #pragma unroll
    for (int it = 0; it < 4; ++it) {
        int p = it * 256 + tid;        // fragment-row index 0..1023
        int g6 = p >> 6;               // kk*4 + nt  (0..15)
        int kk = g6 >> 2, nt = g6 & 3;
        int lane6 = p & 63;
        int lg = lane6 >> 4, lr = lane6 & 15;
        int f = nt * 16 + lr;
        int kbase = kk * 32 + lg * 8;
        bf16x8 hi, lo;
        #pragma unroll
        for (int j = 0; j < 8; ++j) {
            float w = W1[(kbase + j) * FOUT + f];
            short h = f2bf(w);
            hi[j] = h;
            lo[j] = f2bf(w - bf2f(h));
        }
        ((bf16x8*)Wlds)[p] = hi;
        ((bf16x8*)(Wlds + 8192))[p] = lo;
    }
    __syncthreads();

    const int wave = tid >> 6, lane = tid & 63;
    const int lg = lane >> 4, lr = lane & 15;
    const int q = blockIdx.y;
    const int base = blockIdx.x * 128 + wave * 32;
    const float* qb = query + (size_t)q * N * FIN;
    __half* yq = y + (size_t)q * N * FOUT;
    const bf16x8* Bp = (const bf16x8*)Wlds;

    int n0 = base + lr;       if (n0 >= N) n0 = N - 1;
    int n1 = base + 16 + lr;  if (n1 >= N) n1 = N - 1;
    const float4* r0 = (const float4*)(qb + (size_t)n0 * FIN);
    const float4* r1 = (const float4*)(qb + (size_t)n1 * FIN);

    float4 a0[8], a1[8];
    #pragma unroll
    for (int kk = 0; kk < 4; ++kk) {
        a0[2 * kk]     = r0[kk * 8 + lg * 2];
        a0[2 * kk + 1] = r0[kk * 8 + lg * 2 + 1];
        a1[2 * kk]     = r1[kk * 8 + lg * 2];
        a1[2 * kk + 1] = r1[kk * 8 + lg * 2 + 1];
    }

    f32x4 acc0[4], acc1[4];
    #pragma unroll
    for (int nt = 0; nt < 4; ++nt) { acc0[nt] = (f32x4)0.f; acc1[nt] = (f32x4)0.f; }

    #pragma unroll
    for (int kk = 0; kk < 4; ++kk) {
        bf16x8 A0, A1;
        const float* x0 = (const float*)&a0[2 * kk];
        const float* x1 = (const float*)&a1[2 * kk];
        #pragma unroll
        for (int j = 0; j < 8; ++j) { A0[j] = f2bf(x0[j]); A1[j] = f2bf(x1[j]); }
        #pragma unroll
        for (int nt = 0; nt < 4; ++nt) {
            bf16x8 Bhi = Bp[(kk * 4 + nt) * 64 + lane];
            bf16x8 Blo = Bp[1024 + (kk * 4 + nt) * 64 + lane];
            acc0[nt] = __builtin_amdgcn_mfma_f32_16x16x32_bf16(A0, Bhi, acc0[nt], 0, 0, 0);
            acc0[nt] = __builtin_amdgcn_mfma_f32_16x16x32_bf16(A0, Blo, acc0[nt], 0, 0, 0);
            acc1[nt] = __builtin_amdgcn_mfma_f32_16x16x32_bf16(A1, Bhi, acc1[nt], 0, 0, 0);
            acc1[nt] = __builtin_amdgcn_mfma_f32_16x16x32_bf16(A1, Blo, acc1[nt], 0, 0, 0);
        }
    }
    #pragma unroll
    for (int r = 0; r < 4; ++r) {
        int m0 = base + lg * 4 + r;
        int m1 = base + 16 + lg * 4 + r;
        if (m0 < N) {
            #pragma unroll
            for (int nt = 0; nt < 4; ++nt)
                yq[(size_t)m0 * FOUT + nt * 16 + lr] = __float2half(acc0[nt][r]);
        }
        if (m1 < N) {
            #pragma unroll
            for (int nt = 0; nt < 4; ++nt)
                yq[(size_t)m1 * FOUT + nt * 16 + lr] = __float2half(acc1[nt][r]);
        }
    }
}

// ---------------- Stage 2: s1 = tanh(mean_k y[e]+b1).W2 ----------------
// 2 nodes/wave, lane = feature-pair; 8 independent coalesced row gathers.
__global__ __launch_bounds__(256) void k_agg(const __half* __restrict__ y,
                                             const int* __restrict__ edges,
                                             const float* __restrict__ b1,
                                             const float* __restrict__ W2,
                                             float* __restrict__ s1, int N) {
    const int tid = threadIdx.x;
    const int wave = tid >> 6, lane = tid & 63;
    const int half = lane >> 5, fl = lane & 31;
    const int q = blockIdx.y;
    const int n = blockIdx.x * 8 + wave * 2 + half;
    const int nc = n < N ? n : N - 1;
    const __half* yq = y + (size_t)q * N * FOUT;

    const int4* erow = (const int4*)(edges + (size_t)nc * KN);
    int4 ea = erow[0], eb = erow[1];

    const __half2* y2 = (const __half2*)yq;
    __half2 v0 = y2[(size_t)ea.x * 32 + fl];
    __half2 v1 = y2[(size_t)ea.y * 32 + fl];
    __half2 v2 = y2[(size_t)ea.z * 32 + fl];
    __half2 v3 = y2[(size_t)ea.w * 32 + fl];
    __half2 v4 = y2[(size_t)eb.x * 32 + fl];
    __half2 v5 = y2[(size_t)eb.y * 32 + fl];
    __half2 v6 = y2[(size_t)eb.z * 32 + fl];
    __half2 v7 = y2[(size_t)eb.w * 32 + fl];

    __half2 s01 = __hadd2(v0, v1), s23 = __hadd2(v2, v3);
    __half2 s45 = __hadd2(v4, v5), s67 = __hadd2(v6, v7);
    __half2 sum = __hadd2(__hadd2(s01, s23), __hadd2(s45, s67));
    float2 sf = __half22float2(sum);

    float2 bv = *(const float2*)(b1 + fl * 2);
    float2 wv = *(const float2*)(W2 + fl * 2);
    float x0 = sf.x * 0.125f + bv.x;
    float x1 = sf.y * 0.125f + bv.y;
    float a0 = fabsf(x0), a1 = fabsf(x1);
    float e0 = __expf(-2.f * a0), e1 = __expf(-2.f * a1);
    float t0 = __fdividef(1.f - e0, 1.f + e0);
    float t1 = __fdividef(1.f - e1, 1.f + e1);
    t0 = copysignf(t0, x0);
    t1 = copysignf(t1, x1);
    float p = t0 * wv.x + t1 * wv.y;
    #pragma unroll
    for (int off = 16; off; off >>= 1) p += __shfl_xor(p, off);
    if (fl == 0 && n < N) s1[(size_t)q * N + n] = p;
}

// ---------------- Stage 3 (fused): score + exp + Z-partial + weighted values ----------------
__global__ __launch_bounds__(256) void k_ctx(const float* __restrict__ values,
                                             const float* __restrict__ s1,
                                             const int* __restrict__ edges,
                                             const float* __restrict__ b2,
                                             float* __restrict__ score,
                                             float* __restrict__ partial,
                                             float* __restrict__ zpart, int N) {
    const int q = blockIdx.y, cb = blockIdx.x;
    const int tid = threadIdx.x;
    const int chunk = (N + CTXB - 1) / CTXB;     // 200
    const int n0 = cb * chunk, n1 = min(n0 + chunk, N);
    const int cnt = n1 - n0;
    __shared__ float wlds[256];
    __shared__ float zred[4];
    const float* s1q = s1 + (size_t)q * N;
    const float b2v = b2[0];

    // phase 1: scores + exp for this chunk (cnt = 200 <= 256)
    float zp = 0.f;
    if (tid < cnt) {
        int n = n0 + tid;
        float acc = 0.f;
        #pragma unroll
        for (int k = 0; k < KN; ++k) acc += s1q[edges[(size_t)n * KN + k]];
        float sc = acc * 0.125f + b2v;
        score[(size_t)q * N + n] = sc;
        float ex = __expf(sc);
        wlds[tid] = ex;
        zp = ex;
    }
    float z = zp;
    #pragma unroll
    for (int off = 32; off; off >>= 1) z += __shfl_xor(z, off);
    if ((tid & 63) == 0) zred[tid >> 6] = z;
    __syncthreads();

    // phase 2: weighted values stream (unroll-8, independent loads)
    const int fi = tid & 31, g = tid >> 5;
    const float4* v = (const float4*)(values + (size_t)q * N * FIN);
    float4 acc = make_float4(0.f, 0.f, 0.f, 0.f);
    int n = n0 + g;
    for (; n + 56 < n1; n += 64) {
        int l = n - n0;
        float w0 = wlds[l],      w1 = wlds[l + 8],  w2 = wlds[l + 16], w3 = wlds[l + 24];
        float w4 = wlds[l + 32], w5 = wlds[l + 40], w6 = wlds[l + 48], w7 = wlds[l + 56];
        float4 v0 = v[(size_t)n * 32 + fi];
        float4 v1 = v[(size_t)(n + 8) * 32 + fi];
        float4 v2 = v[(size_t)(n + 16) * 32 + fi];
        float4 v3 = v[(size_t)(n + 24) * 32 + fi];
        float4 v4 = v[(size_t)(n + 32) * 32 + fi];
        float4 v5 = v[(size_t)(n + 40) * 32 + fi];
        float4 v6 = v[(size_t)(n + 48) * 32 + fi];
        float4 v7 = v[(size_t)(n + 56) * 32 + fi];
        acc.x = fmaf(w0, v0.x, acc.x); acc.y = fmaf(w0, v0.y, acc.y);
        acc.z = fmaf(w0, v0.z, acc.z); acc.w = fmaf(w0, v0.w, acc.w);
        acc.x = fmaf(w1, v1.x, acc.x); acc.y = fmaf(w1, v1.y, acc.y);
        acc.z = fmaf(w1, v1.z, acc.z); acc.w = fmaf(w1, v1.w, acc.w);
        acc.x = fmaf(w2, v2.x, acc.x); acc.y = fmaf(w2, v2.y, acc.y);
        acc.z = fmaf(w2, v2.z, acc.z); acc.w = fmaf(w2, v2.w, acc.w);
        acc.x = fmaf(w3, v3.x, acc.x); acc.y = fmaf(w3, v3.y, acc.y);
        acc.z = fmaf(w3, v3.z, acc.z); acc.w = fmaf(w3, v3.w, acc.w);
        acc.x = fmaf(w4, v4.x, acc.x); acc.y = fmaf(w4, v4.y, acc.y);
        acc.z = fmaf(w4, v4.z, acc.z); acc.w = fmaf(w4, v4.w, acc.w);
        acc.x = fmaf(w5, v5.x, acc.x); acc.y = fmaf(w5, v5.y, acc.y);
        acc.z = fmaf(w5, v5.z, acc.z); acc.w = fmaf(w5, v5.w, acc.w);
        acc.x = fmaf(w6, v6.x, acc.x); acc.y = fmaf(w6, v6.y, acc.y);
        acc.z = fmaf(w6, v6.z, acc.z); acc.w = fmaf(w6, v6.w, acc.w);
        acc.x = fmaf(w7, v7.x, acc.x); acc.y = fmaf(w7, v7.y, acc.y);
        acc.z = fmaf(w7, v7.z, acc.z); acc.w = fmaf(w7, v7.w, acc.w);
    }
    for (; n < n1; n += 8) {
        float ww = wlds[n - n0];
        float4 a = v[(size_t)n * 32 + fi];
        acc.x = fmaf(ww, a.x, acc.x);
        acc.y = fmaf(ww, a.y, acc.y);
        acc.z = fmaf(ww, a.z, acc.z);
        acc.w = fmaf(ww, a.w, acc.w);
    }
    __shared__ float4 part[256];
    part[tid] = acc;
    __syncthreads();
    if (tid < 32) {
        float4 a = part[tid];
        #pragma unroll
        for (int gg = 1; gg < 8; ++gg) {
            float4 b = part[gg * 32 + tid];
            a.x += b.x; a.y += b.y; a.z += b.z; a.w += b.w;
        }
        ((float4*)partial)[((size_t)q * CTXB + cb) * 32 + fi] = a;
    }
    if (tid == 0) zpart[(size_t)q * CTXB + cb] = zred[0] + zred[1] + zred[2] + zred[3];
}

// ---------------- Stage 4: ctx[q,f] = (Σ_cb partial[q,cb,f]) / (Σ_cb zpart[q,cb]) ----------------
__global__ __launch_bounds__(512) void k_final(const float* __restrict__ partial,
                                               const float* __restrict__ zpart,
                                               float* __restrict__ ctx) {
    const int q = blockIdx.x;
    const int tid = threadIdx.x;
    const int f = tid & 127, h = tid >> 7;
    const float* p = partial + (size_t)q * CTXB * FIN;
    float s = 0.f;
    for (int b = h; b < CTXB; b += 4) s += p[(size_t)b * FIN + f];
    __shared__ float red[512];
    __shared__ float zred[8];
    red[tid] = s;
    float z = (tid < CTXB) ? zpart[(size_t)q * CTXB + tid] : 0.f;
    #pragma unroll
    for (int off = 32; off; off >>= 1) z += __shfl_xor(z, off);
    if ((tid & 63) == 0) zred[tid >> 6] = z;
    __syncthreads();
    if (tid < 128) {
        float Zt = zred[0] + zred[1] + zred[2] + zred[3] +
                   zred[4] + zred[5] + zred[6] + zred[7];
        float t = red[tid] + red[tid + 128] + red[tid + 256] + red[tid + 384];
        ctx[q * FIN + f] = t * (1.f / Zt);
    }
}

extern "C" void kernel_launch(void* const* d_in, const int* in_sizes, int n_in,
                              void* d_out, int out_size, void* d_ws, size_t ws_size,
                              hipStream_t stream) {
    const float* query  = (const float*)d_in[0];
    const float* values = (const float*)d_in[1];
    const int*   edges  = (const int*)d_in[2];
    const float* W1     = (const float*)d_in[3];
    const float* b1     = (const float*)d_in[4];
    const float* W2     = (const float*)d_in[5];
    const float* b2     = (const float*)d_in[6];

    const int N = in_sizes[2] / KN;           // 50000
    const int Q = in_sizes[0] / (N * FIN);    // 4

    float* out   = (float*)d_out;
    float* ctx   = out;                       // [Q,128]
    float* score = out + (size_t)Q * FIN;     // [Q,N]

    char* ws = (char*)d_ws;
    __half* y = (__half*)ws;                                    // [Q,N,64] f16
    size_t off = (size_t)Q * N * FOUT * sizeof(__half);
    float* s1    = (float*)(ws + off);  off += (size_t)Q * N * sizeof(float);
    float* part  = (float*)(ws + off);  off += (size_t)Q * CTXB * FIN * sizeof(float);
    float* zpart = (float*)(ws + off);                          // [Q,CTXB]

    dim3 g1((N + 127) / 128, Q);
    k_xw<<<g1, 256, 0, stream>>>(query, W1, y, N);
    dim3 g2((N + 7) / 8, Q);
    k_agg<<<g2, 256, 0, stream>>>(y, edges, b1, W2, s1, N);
    dim3 g3(CTXB, Q);
    k_ctx<<<g3, 256, 0, stream>>>(values, s1, edges, b2, score, part, zpart, N);
    k_final<<<Q, 512, 0, stream>>>(part, zpart, ctx);
}